// Round 1
// baseline (230.445 us; speedup 1.0000x reference)
//
#include <hip/hip_runtime.h>
#include <hip/hip_bf16.h>

// Encoding layer, single-pass MFMA implementation.
// B=16, C=512, N=64*64=4096, K=32 codewords.
// Grid: 512 blocks (b = blk>>5, n-chunk = blk&31, 128 tokens/block in 4 groups of 32).
// Block: 256 threads = 4 waves. LDS 61.3 KiB -> 2 blocks/CU.

#define B_ 16
#define C_ 512
#define N_ 4096
#define K_ 32
#define XCPAD 40   // n-stride of XC tile (bf16 elems); 80 B rows keep b128 16B-aligned

typedef __attribute__((ext_vector_type(8))) short short8;
typedef __attribute__((ext_vector_type(16))) float floatx16;

__device__ inline unsigned short f2bf(float f) {
    union { float f; unsigned u; } v; v.f = f;
    unsigned r = v.u + 0x7FFFu + ((v.u >> 16) & 1u);  // RNE
    return (unsigned short)(r >> 16);
}

__global__ __launch_bounds__(256, 2)
void enc_kernel(const float* __restrict__ x, const float* __restrict__ cw,
                const float* __restrict__ scale, float* __restrict__ out)
{
    __shared__ unsigned short XC[C_ * XCPAD];   // x tile bf16, [c][n], 40960 B
    __shared__ float Spart[4][32][33];          // per-wave partial S'[n][k], 16896 B
    __shared__ unsigned short Wl[K_ * XCPAD];   // softmax weights bf16 [k][n], 2560 B
    __shared__ float xsqp[4][32];               // per-wave partial ||x_n||^2
    __shared__ float csq[K_];
    __shared__ float scl[K_];
    __shared__ float wsumL[K_];

    const int tid  = threadIdx.x;
    const int wave = tid >> 6;
    const int lane = tid & 63;
    const int l31  = lane & 31;
    const int lh   = lane >> 5;

    const int b     = blockIdx.x >> 5;
    const int chunk = blockIdx.x & 31;
    const long xbase = (long)b * C_ * N_;

    // ---- P0: scale, c_sq ----
    if (tid < K_) scl[tid] = scale[tid];
    {
        const int k = tid >> 3, p = tid & 7;
        const float4* cwr = (const float4*)(cw + k * C_ + p * 64);
        float s = 0.f;
        #pragma unroll
        for (int i = 0; i < 16; ++i) {
            float4 v = cwr[i];
            s += v.x*v.x + v.y*v.y + v.z*v.z + v.w*v.w;
        }
        s += __shfl_xor(s, 1); s += __shfl_xor(s, 2); s += __shfl_xor(s, 4);
        if (p == 0) csq[k] = s;
    }

    // ---- preload GEMM1 B-frags: cw^T for this wave's 128-c range ----
    // B[kk=c][col=k]: col = l31 (codeword), kk = lh*8 + j  -> cw[l31][cbase + lh*8 + j]
    short8 cwf[8];
    #pragma unroll
    for (int s = 0; s < 8; ++s) {
        const float* p = cw + l31 * C_ + wave * 128 + s * 16 + lh * 8;
        short8 f;
        #pragma unroll
        for (int j = 0; j < 8; ++j) f[j] = (short)f2bf(p[j]);
        cwf[s] = f;
    }

    floatx16 acc[4];            // GEMM2 accum: 4 c-tiles of 32 for this wave
    floatx16 accW;              // ones-tile (wave 0 only): wsum[k]
    #pragma unroll
    for (int t = 0; t < 4; ++t)
        #pragma unroll
        for (int i = 0; i < 16; ++i) acc[t][i] = 0.f;
    #pragma unroll
    for (int i = 0; i < 16; ++i) accW[i] = 0.f;

    __syncthreads();

    for (int g = 0; g < 4; ++g) {
        const int n0 = chunk * 128 + g * 32;

        // ---- staging: x[b, :, n0..n0+31] fp32 -> bf16 LDS + fp32 ||x||^2 partials ----
        {
            const int c0 = tid >> 3;   // 0..31
            const int nq = tid & 7;    // n-quad
            float sq0 = 0.f, sq1 = 0.f, sq2 = 0.f, sq3 = 0.f;
            #pragma unroll
            for (int it = 0; it < 16; ++it) {
                const int c = c0 + 32 * it;
                const float4 v = *(const float4*)(x + xbase + (long)c * N_ + n0 + nq * 4);
                sq0 += v.x*v.x; sq1 += v.y*v.y; sq2 += v.z*v.z; sq3 += v.w*v.w;
                const unsigned lo = (unsigned)f2bf(v.x) | ((unsigned)f2bf(v.y) << 16);
                const unsigned hi = (unsigned)f2bf(v.z) | ((unsigned)f2bf(v.w) << 16);
                *(uint2*)&XC[c * XCPAD + nq * 4] = make_uint2(lo, hi);
            }
            // reduce over the 8 c0-values resident in this wave (lane bits 3..5)
            #pragma unroll
            for (int m = 8; m <= 32; m <<= 1) {
                sq0 += __shfl_xor(sq0, m); sq1 += __shfl_xor(sq1, m);
                sq2 += __shfl_xor(sq2, m); sq3 += __shfl_xor(sq3, m);
            }
            if (((tid >> 3) & 7) == 0) {
                xsqp[wave][nq * 4 + 0] = sq0; xsqp[wave][nq * 4 + 1] = sq1;
                xsqp[wave][nq * 4 + 2] = sq2; xsqp[wave][nq * 4 + 3] = sq3;
            }
        }
        __syncthreads();

        // ---- GEMM1: S'[n][k] partial over wave's c-range (X^T @ cw^T) ----
        {
            floatx16 S;
            #pragma unroll
            for (int i = 0; i < 16; ++i) S[i] = 0.f;
            #pragma unroll
            for (int s = 0; s < 8; ++s) {
                const int cb = wave * 128 + s * 16 + lh * 8;
                short8 a;   // A[m=n=l31][kk=c]: XC[cb+j][l31], strided u16 reads
                #pragma unroll
                for (int j = 0; j < 8; ++j)
                    a[j] = (short)XC[(cb + j) * XCPAD + l31];
                S = __builtin_amdgcn_mfma_f32_32x32x16_bf16(a, cwf[s], S, 0, 0, 0);
            }
            #pragma unroll
            for (int r = 0; r < 16; ++r) {
                const int n = (r & 3) + 8 * (r >> 2) + 4 * lh;   // C/D row
                Spart[wave][n][l31] = S[r];                      // col = k = l31
            }
        }
        __syncthreads();

        // ---- softmax over k (fp32) ----
        {
            const int n  = tid >> 3;
            const int kq = tid & 7;
            const float xq = xsqp[0][n] + xsqp[1][n] + xsqp[2][n] + xsqp[3][n];
            float L[4];
            #pragma unroll
            for (int i = 0; i < 4; ++i) {
                const int k = kq * 4 + i;
                const float s2 = Spart[0][n][k] + Spart[1][n][k]
                               + Spart[2][n][k] + Spart[3][n][k];
                L[i] = scl[k] * (xq - 2.f * s2 + csq[k]);
            }
            float m = fmaxf(fmaxf(L[0], L[1]), fmaxf(L[2], L[3]));
            m = fmaxf(m, __shfl_xor(m, 1));
            m = fmaxf(m, __shfl_xor(m, 2));
            m = fmaxf(m, __shfl_xor(m, 4));
            float e[4], sum = 0.f;
            #pragma unroll
            for (int i = 0; i < 4; ++i) { e[i] = __expf(L[i] - m); sum += e[i]; }
            sum += __shfl_xor(sum, 1); sum += __shfl_xor(sum, 2); sum += __shfl_xor(sum, 4);
            const float inv = 1.f / sum;
            #pragma unroll
            for (int i = 0; i < 4; ++i)
                Wl[(kq * 4 + i) * XCPAD + n] = f2bf(e[i] * inv);
        }
        __syncthreads();

        // ---- GEMM2: acc[k][c] += W @ X^T over this group's 32 tokens ----
        {
            short8 aw[2];   // A[m=k=l31][kk=n]: Wl[l31][sub*16 + lh*8 ..+7], b128
            #pragma unroll
            for (int sub = 0; sub < 2; ++sub)
                aw[sub] = *(const short8*)&Wl[l31 * XCPAD + sub * 16 + lh * 8];
            #pragma unroll
            for (int t4 = 0; t4 < 4; ++t4) {
                const int crow = (wave * 4 + t4) * 32 + l31;   // B col = c
                #pragma unroll
                for (int sub = 0; sub < 2; ++sub) {
                    const short8 bx = *(const short8*)&XC[crow * XCPAD + sub * 16 + lh * 8];
                    acc[t4] = __builtin_amdgcn_mfma_f32_32x32x16_bf16(aw[sub], bx, acc[t4], 0, 0, 0);
                }
            }
            if (wave == 0) {
                short8 ones;
                #pragma unroll
                for (int j = 0; j < 8; ++j) ones[j] = (short)0x3F80;  // bf16 1.0
                #pragma unroll
                for (int sub = 0; sub < 2; ++sub)
                    accW = __builtin_amdgcn_mfma_f32_32x32x16_bf16(aw[sub], ones, accW, 0, 0, 0);
            }
        }
        __syncthreads();   // protect XC/Wl/Spart/xsqp before next staging
    }

    // ---- epilogue ----
    if (wave == 0 && l31 == 0) {        // lanes 0 and 32 cover all 32 rows
        #pragma unroll
        for (int r = 0; r < 16; ++r) {
            const int k = (r & 3) + 8 * (r >> 2) + 4 * lh;
            wsumL[k] = accW[r];
        }
    }
    __syncthreads();

    #pragma unroll
    for (int t4 = 0; t4 < 4; ++t4) {
        const int c = (wave * 4 + t4) * 32 + l31;
        #pragma unroll
        for (int r = 0; r < 16; ++r) {
            const int k = (r & 3) + 8 * (r >> 2) + 4 * lh;
            const float val = acc[t4][r] - wsumL[k] * cw[k * C_ + c];
            atomicAdd(out + ((b * K_ + k) * C_ + c), val);
        }
    }
}

extern "C" void kernel_launch(void* const* d_in, const int* in_sizes, int n_in,
                              void* d_out, int out_size, void* d_ws, size_t ws_size,
                              hipStream_t stream) {
    const float* x     = (const float*)d_in[0];
    const float* cw    = (const float*)d_in[1];
    const float* scale = (const float*)d_in[2];
    float* out = (float*)d_out;
    hipMemsetAsync(out, 0, (size_t)out_size * sizeof(float), stream);
    hipLaunchKernelGGL(enc_kernel, dim3(B_ * 32), dim3(256), 0, stream,
                       x, cw, scale, out);
}